// Round 4
// baseline (320.569 us; speedup 1.0000x reference)
//
#include <hip/hip_runtime.h>

// Problem constants (fixed by setup_inputs: B=64, C=16, T=32768, fp32)
#define B_BATCH 64
#define C_CH    16
#define T_LEN   32768
#define NROWS   (B_BATCH * C_CH)       // 1024 rows, one WAVE per row
#define WSZ     64                     // block = 1 wave, no barriers anywhere
#define CHUNK   256                    // elems per chunk (64 lanes x float4)
#define NCHUNK  (T_LEN / CHUNK)        // 128 chunks per row
#define DEPTH   16                     // prefetch ring depth (chunks in flight)

struct WsLayout { double sum; unsigned int done; unsigned int pad; };

// DPP-based add: x + (x moved by CTRL), invalid lanes contribute 0.
// Full-rate VALU — no ds_permute / lgkmcnt in the serial chain.
template<int CTRL, int RM>
__device__ __forceinline__ float dpp_add(float x) {
    int t = __builtin_amdgcn_update_dpp(0, __builtin_bit_cast(int, x),
                                        CTRL, RM, 0xF, false);
    return x + __builtin_bit_cast(float, t);
}

// 64-lane inclusive scan via DPP (AMDGPUAtomicOptimizer sequence):
// row_shr:1,2,4,8 within 16-lane rows, then row_bcast:15 (rows 1,3),
// row_bcast:31 (rows 2,3) to stitch rows together.
__device__ __forceinline__ float wave_incl_scan(float v) {
    v = dpp_add<0x111, 0xF>(v);   // row_shr:1
    v = dpp_add<0x112, 0xF>(v);   // row_shr:2
    v = dpp_add<0x114, 0xF>(v);   // row_shr:4
    v = dpp_add<0x118, 0xF>(v);   // row_shr:8
    v = dpp_add<0x142, 0xA>(v);   // row_bcast:15 -> rows 1,3
    v = dpp_add<0x143, 0xC>(v);   // row_bcast:31 -> rows 2,3
    return v;
}

__global__ __launch_bounds__(WSZ, 1) void wloss_kernel(
    const float* __restrict__ pred,
    const float* __restrict__ tru,
    WsLayout* __restrict__ ws,
    float* __restrict__ out)
{
    const int row  = blockIdx.x;
    const int lane = threadIdx.x;      // 0..63, single wave

    const float4* p4 = (const float4*)(pred + (size_t)row * T_LEN);
    const float4* t4 = (const float4*)(tru  + (size_t)row * T_LEN);

    // ---- prefetch ring: DEPTH chunks of (p,t) float4s in registers ----
    float4 pb[DEPTH], tb[DEPTH];
    #pragma unroll
    for (int k = 0; k < DEPTH; ++k) {
        pb[k] = p4[k * 64 + lane];     // coalesced: lanes at 16B stride
        tb[k] = t4[k * 64 + lane];
    }

    float  carry = 0.0f;               // wave-uniform running cumsum (SGPR)
    double acc   = 0.0;

    #pragma unroll 1
    for (int base = 0; base < NCHUNK; base += DEPTH) {
        #pragma unroll
        for (int k = 0; k < DEPTH; ++k) {
            const int c = base + k;
            float4 p = pb[k];
            float4 t = tb[k];

            // refill this ring slot from DEPTH chunks ahead (uniform branch)
            const int nc = c + DEPTH;
            if (nc < NCHUNK) {
                pb[k] = p4[nc * 64 + lane];
                tb[k] = t4[nc * 64 + lane];
            }

            // local inclusive scan of 4 diffs
            float d0 = p.x - t.x;
            float d1 = p.y - t.y;
            float d2 = p.z - t.z;
            float d3 = p.w - t.w;
            float s1 = d0;
            float s2 = s1 + d1;
            float s3 = s2 + d2;
            float s4 = s3 + d3;

            // wave inclusive scan of per-lane totals — pure VALU (DPP)
            float v = wave_incl_scan(s4);

            // chunk total: lane 63 -> SGPR (cheap, no LDS)
            float ctot = __builtin_bit_cast(float,
                __builtin_amdgcn_readlane(__builtin_bit_cast(int, v), 63));

            const float excl = carry + (v - s4);   // exclusive prefix, global

            const int   e0 = c * CHUNK + lane * 4;
            const float w0 = (float)(T_LEN - e0);

            float part = fabsf(excl + s1) * w0
                       + fabsf(excl + s2) * (w0 - 1.0f)
                       + fabsf(excl + s3) * (w0 - 2.0f)
                       + fabsf(excl + s4) * (w0 - 3.0f);
            acc += (double)part;       // fp32 chunk partial (<~1e9) -> double

            carry += ctot;             // the only serial cross-chunk dependency
        }
    }

    // ---- wave reduction of double acc (epilogue, runs once) ----
    #pragma unroll
    for (int off = 32; off > 0; off >>= 1)
        acc += __shfl_down(acc, off, 64);

    if (lane == 0) {
        atomicAdd(&ws->sum, acc);              // device-scope f64 atomic
        __threadfence();
        unsigned int prev = atomicAdd(&ws->done, 1u);
        if (prev == NROWS - 1) {               // last wave finalizes
            double total = atomicAdd(&ws->sum, 0.0);   // atomic read
            const double tc_     = (double)T_LEN * (double)C_CH;
            const double scaling = 2.0 / (tc_ * (tc_ + 1.0));
            out[0] = (float)(total * scaling / (double)B_BATCH);
        }
    }
}

extern "C" void kernel_launch(void* const* d_in, const int* in_sizes, int n_in,
                              void* d_out, int out_size, void* d_ws, size_t ws_size,
                              hipStream_t stream)
{
    const float* pred = (const float*)d_in[0];
    const float* tru  = (const float*)d_in[1];
    WsLayout*    ws   = (WsLayout*)d_ws;
    float*       out  = (float*)d_out;

    // d_ws re-poisoned to 0xAA before every launch -> zero accumulator+counter
    hipMemsetAsync(ws, 0, sizeof(WsLayout), stream);

    wloss_kernel<<<NROWS, WSZ, 0, stream>>>(pred, tru, ws, out);
}